// Round 16
// baseline (158.429 us; speedup 1.0000x reference)
//
#include <hip/hip_runtime.h>
#include <hip/hip_bf16.h>

typedef unsigned short u16;
typedef unsigned long long u64;
typedef __attribute__((ext_vector_type(8))) short bf16x8;
typedef __attribute__((ext_vector_type(4))) float f32x4;

#define NB 16
#define NN 2048
#define FF 256
#define LOG2E 1.4426950408889634f

__device__ __forceinline__ u16 f2bf(float x) {
    union { float f; unsigned u; } v; v.f = x;
    unsigned r = v.u + 0x7fffu + ((v.u >> 16) & 1u);
    return (u16)(r >> 16);
}

#define GLD_LDS(g, l) __builtin_amdgcn_global_load_lds((const __attribute__((address_space(1))) void*)(g), (__attribute__((address_space(3))) void*)(l), 16, 0, 0)

// ---------------- Kernel A: u1 = W@a1, u2 = W@a2 (fp32), WT = W^T in bf16 ----------------
__global__ __launch_bounds__(256) void k_prep_w(const float* __restrict__ W, const float* __restrict__ a,
                                                u16* __restrict__ WT, float* __restrict__ u1, float* __restrict__ u2) {
    int b = blockIdx.y, t = threadIdx.x;
    __shared__ float a1s[FF], a2s[FF];
    a1s[t] = a[b*2*FF + t];
    a2s[t] = a[b*2*FF + FF + t];
    __syncthreads();
    int f = blockIdx.x*64 + (t >> 2);
    int o0 = (t & 3) * 64;
    const float* wrow = W + (size_t)(b*FF + f)*FF + o0;
    u16* wtb = WT + (size_t)b*FF*FF;
    float s1 = 0.f, s2 = 0.f;
#pragma unroll
    for (int c = 0; c < 16; ++c) {
        float4 v = *(const float4*)(wrow + c*4);
        int o = o0 + c*4;
        s1 += v.x*a1s[o] + v.y*a1s[o+1] + v.z*a1s[o+2] + v.w*a1s[o+3];
        s2 += v.x*a2s[o] + v.y*a2s[o+1] + v.z*a2s[o+2] + v.w*a2s[o+3];
        wtb[(size_t)(o+0)*FF + f] = f2bf(v.x);
        wtb[(size_t)(o+1)*FF + f] = f2bf(v.y);
        wtb[(size_t)(o+2)*FF + f] = f2bf(v.z);
        wtb[(size_t)(o+3)*FF + f] = f2bf(v.w);
    }
    s1 += __shfl_xor(s1, 1); s1 += __shfl_xor(s1, 2);
    s2 += __shfl_xor(s2, 1); s2 += __shfl_xor(s2, 2);
    if ((t & 3) == 0) { u1[b*FF + f] = s1; u2[b*FF + f] = s2; }
}

// ---------------- Kernel B (fused): WhT = (h@W)^T bf16 (linear), Wh1/Wh2 fp32*log2e ----------------
__global__ __launch_bounds__(256) void k_wh(const float* __restrict__ h, const u16* __restrict__ WT,
                                            const float* __restrict__ u1, const float* __restrict__ u2,
                                            u16* __restrict__ WhT, float* __restrict__ Wh1, float* __restrict__ Wh2) {
    int bid = blockIdx.x;
    int nid = (bid & 7)*64 + (bid >> 3);
    int b  = nid >> 5;
    int i0 = (nid & 31) * 64;
    int t = threadIdx.x, lane = t & 63, wave = t >> 6;
    __shared__ alignas(16) u16 At[256*64];
    __shared__ alignas(16) u16 Bt[64*64];
    __shared__ float u1s[FF], u2s[FF];
    u1s[t] = u1[b*FF + t];
    u2s[t] = u2[b*FF + t];

    const u16*   WTb = WT + (size_t)b*FF*FF;
    const float* hb  = h + ((size_t)b*NN + i0)*FF;
    int r = t >> 2, q = t & 3, kq = q*16;

    f32x4 acc[4][4];
#pragma unroll
    for (int x = 0; x < 4; ++x)
#pragma unroll
        for (int y = 0; y < 4; ++y) acc[x][y] = (f32x4)0.f;
    float s1 = 0.f, s2 = 0.f;
    __syncthreads();

#pragma unroll 1
    for (int kk = 0; kk < 4; ++kk) {
        int k0 = kk*64;
#pragma unroll
        for (int is = 0; is < 8; ++is) {
            int s = is*256 + t;
            int row = s >> 3, jbp = s & 7;
            int jbl = jbp ^ (row & 7);
            GLD_LDS(WTb + (size_t)row*FF + k0 + jbl*8, &At[s*8]);
        }
        {
            const float* hp = hb + (size_t)r*FF + k0 + kq;
            float4 f0 = *(const float4*)(hp + 0);
            float4 f1 = *(const float4*)(hp + 4);
            float4 f2 = *(const float4*)(hp + 8);
            float4 f3 = *(const float4*)(hp + 12);
            float fv[16] = {f0.x,f0.y,f0.z,f0.w, f1.x,f1.y,f1.z,f1.w,
                            f2.x,f2.y,f2.z,f2.w, f3.x,f3.y,f3.z,f3.w};
            union { u16 u[16]; bf16x8 v[2]; } cv;
#pragma unroll
            for (int e = 0; e < 16; ++e) {
                int kidx = k0 + kq + e;
                s1 += fv[e]*u1s[kidx];
                s2 += fv[e]*u2s[kidx];
                cv.u[e] = f2bf(fv[e]);
            }
            int rx = r & 7;
            *(bf16x8*)&Bt[r*64 + ((q*2 + 0) ^ rx)*8] = cv.v[0];
            *(bf16x8*)&Bt[r*64 + ((q*2 + 1) ^ rx)*8] = cv.v[1];
        }
        __syncthreads();
#pragma unroll
        for (int kc = 0; kc < 2; ++kc) {
            int jl = kc*4 + (lane >> 4);
            bf16x8 af[4], bfr[4];
#pragma unroll
            for (int mi = 0; mi < 4; ++mi) {
                int rr2 = wave*64 + mi*16 + (lane & 15);
                af[mi] = *(const bf16x8*)&At[rr2*64 + ((jl ^ (rr2 & 7))*8)];
            }
#pragma unroll
            for (int ni = 0; ni < 4; ++ni) {
                int rr2 = ni*16 + (lane & 15);
                bfr[ni] = *(const bf16x8*)&Bt[rr2*64 + ((jl ^ (rr2 & 7))*8)];
            }
#pragma unroll
            for (int mi = 0; mi < 4; ++mi)
#pragma unroll
                for (int ni = 0; ni < 4; ++ni)
                    acc[mi][ni] = __builtin_amdgcn_mfma_f32_16x16x32_bf16(af[mi], bfr[ni], acc[mi][ni], 0, 0, 0);
        }
        __syncthreads();
    }
    s1 += __shfl_xor(s1, 1); s1 += __shfl_xor(s1, 2);
    s2 += __shfl_xor(s2, 1); s2 += __shfl_xor(s2, 2);
    if (q == 0) { Wh1[b*NN + i0 + r] = s1*LOG2E; Wh2[b*NN + i0 + r] = s2*LOG2E; }

    u16* Wo = WhT + (size_t)b*FF*NN;
#pragma unroll
    for (int mi = 0; mi < 4; ++mi)
#pragma unroll
        for (int ni = 0; ni < 4; ++ni) {
            int i = i0 + ni*16 + (lane & 15);
#pragma unroll
            for (int rr = 0; rr < 4; ++rr) {
                int o = wave*64 + mi*16 + (lane >> 4)*4 + rr;
                Wo[(size_t)o*NN + i] = f2bf(acc[mi][ni][rr]);
            }
        }
}

// ---------------- Kernel D: adj -> bitmask + separable exp-sums, 32-row chunks (4 blocks/CU) ----------------
__global__ __launch_bounds__(256) void k_pack(const int* __restrict__ adj, const float* __restrict__ Wh1,
                                              const float* __restrict__ Wh2, float* __restrict__ pS,
                                              u64* __restrict__ packed) {
    int b = blockIdx.y, ic = blockIdx.x;      // ic: 0..63, 32-row chunk
    int t = threadIdx.x;
    __shared__ float wh1s[32], e1ps[32], e1ns[32];
    __shared__ unsigned char mk[32][256];      // 8KB mask staging
    int ibase = ic*32;
    if (t < 32) {
        float w1 = Wh1[b*NN + ibase + t];
        wh1s[t] = w1;
        e1ps[t] = __builtin_amdgcn_exp2f(w1);
        e1ns[t] = __builtin_amdgcn_exp2f(0.2f*w1);
    }
    float w2[8];
    {
        float4 a0 = *(const float4*)(Wh2 + b*NN + t*8);
        float4 a1 = *(const float4*)(Wh2 + b*NN + t*8 + 4);
        w2[0]=a0.x; w2[1]=a0.y; w2[2]=a0.z; w2[3]=a0.w;
        w2[4]=a1.x; w2[5]=a1.y; w2[6]=a1.z; w2[7]=a1.w;
    }
    __syncthreads();
    const int* abase = adj + ((size_t)(b*NN + ibase))*NN + t*8;
    float sp[8] = {0.f,0.f,0.f,0.f,0.f,0.f,0.f,0.f};
    float sn[8] = {0.f,0.f,0.f,0.f,0.f,0.f,0.f,0.f};
#pragma unroll 1
    for (int r4 = 0; r4 < 8; ++r4) {
        int4 v[4][2];
#pragma unroll
        for (int k = 0; k < 4; ++k) {
            v[k][0] = *(const int4*)(abase + (size_t)(r4*4 + k)*NN);
            v[k][1] = *(const int4*)(abase + (size_t)(r4*4 + k)*NN + 4);
        }
#pragma unroll
        for (int k = 0; k < 4; ++k) {
            int row = r4*4 + k;
            float w1 = wh1s[row], ep = e1ps[row], en = e1ns[row];
            int a[8] = {v[k][0].x, v[k][0].y, v[k][0].z, v[k][0].w,
                        v[k][1].x, v[k][1].y, v[k][1].z, v[k][1].w};
            unsigned bits = 0;
#pragma unroll
            for (int e = 0; e < 8; ++e) {
                bool bit = a[e] > 0;
                bool pos = (w1 + w2[e]) > 0.f;
                bits |= bit ? (1u << e) : 0u;
                sp[e] += (bit && pos)  ? ep : 0.f;
                sn[e] += (bit && !pos) ? en : 0.f;
            }
            mk[row][t] = (unsigned char)bits;
        }
    }
    __syncthreads();
    // flush masks: g = t>>3 (0..31), rows (t&7)*4 .. +3 (32B contiguous per thread)
    {
        int g = t >> 3, r0 = (t & 7)*4;
        u64* dst = packed + ((size_t)(b*32 + g))*NN + ibase + r0;
#pragma unroll
        for (int k = 0; k < 4; ++k)
            dst[k] = *(const u64*)&mk[r0 + k][g*8];
    }
    // partial sums for this 32-row chunk
    {
        float o8[8];
#pragma unroll
        for (int e = 0; e < 8; ++e) {
            float E2p = __builtin_amdgcn_exp2f(w2[e]);
            float E2n = __builtin_amdgcn_exp2f(0.2f*w2[e]);
            o8[e] = E2p*sp[e] + E2n*sn[e];
        }
        float4* po = (float4*)(pS + ((size_t)(b*64 + ic))*NN + t*8);
        po[0] = make_float4(o8[0],o8[1],o8[2],o8[3]);
        po[1] = make_float4(o8[4],o8[5],o8[6],o8[7]);
    }
}

// ---------------- Kernel F: out = elu( att @ Wh ), R13 config, separable-exp genA ----------------
__global__ __launch_bounds__(512, 1) void k_gemm3(const u16* __restrict__ WhT, const u64* __restrict__ packed,
                                                  const float* __restrict__ Wh1, const float* __restrict__ Wh2,
                                                  const float* __restrict__ pS, float* __restrict__ out) {
    int bid = blockIdx.x;
    int nid = (bid & 7)*32 + (bid >> 3);
    int b  = nid >> 4;
    int i0 = (nid & 15) * 128;
    int t = threadIdx.x, lane = t & 63, wave = t >> 6;
    int wm = wave >> 2, wn = wave & 3;
    __shared__ alignas(16) u16 At[2][128*64];
    __shared__ alignas(16) u16 Bt[3][256*64];
    __shared__ float wh2s[NN];
    __shared__ float e2ps[NN];
    __shared__ float e2ns[NN];
    __shared__ unsigned zlut[4];

    const u16* Wo = WhT + (size_t)b*FF*NN;
    int rA = t >> 2, qA = t & 3;
    const u64* pkbase = packed + (size_t)b*32*NN + i0 + rA;   // tile g mask at pkbase[g*NN]

    float wh1r = Wh1[b*NN + i0 + rA];
    float e1p = __builtin_amdgcn_exp2f(wh1r);
    float e1n = __builtin_amdgcn_exp2f(0.2f*wh1r);

    // tables: vectorized sum over 64 partial chunks (L2-hot), then exp2 once per j
    {
        int idx = t*4;
        float4 s4 = make_float4(0.f, 0.f, 0.f, 0.f);
        const float* pb = pS + (size_t)b*64*NN + idx;
#pragma unroll 1
        for (int cc = 0; cc < 64; ++cc) {
            float4 v = *(const float4*)(pb + (size_t)cc*NN);
            s4.x += v.x; s4.y += v.y; s4.z += v.z; s4.w += v.w;
        }
        float4 w2v = *(const float4*)(Wh2 + b*NN + idx);
        float sv[4] = {s4.x, s4.y, s4.z, s4.w};
        float wv[4] = {w2v.x, w2v.y, w2v.z, w2v.w};
#pragma unroll
        for (int e = 0; e < 4; ++e) {
            float inv = (sv[e] > 0.f) ? 1.0f/sv[e] : 0.0f;
            wh2s[idx + e] = wv[e];
            e2ps[idx + e] = __builtin_amdgcn_exp2f(wv[e]) * inv;
            e2ns[idx + e] = __builtin_amdgcn_exp2f(0.2f*wv[e]) * inv;
        }
    }
    if (t < 4) zlut[t] = ((t & 1) ? 0xFFFFu : 0u) | ((t & 2) ? 0xFFFF0000u : 0u);

    auto stageB = [&](int kk, int bbuf) {
        int k0 = kk*64;
#pragma unroll
        for (int is = 0; is < 4; ++is) {
            int s = is*512 + t;
            int row = s >> 3, jbp = s & 7;
            int jbl = jbp ^ (row & 7);
            GLD_LDS(Wo + (size_t)row*NN + k0 + jbl*8, &Bt[bbuf][s*8]);
        }
    };
    auto genA = [&](int g, int abuf, unsigned mask16) {
        int rx = rA & 7;
#pragma unroll
        for (int hf = 0; hf < 2; ++hf) {
            union { unsigned w[4]; bf16x8 v; } ob;
#pragma unroll
            for (int q4 = 0; q4 < 2; ++q4) {
                int jb = g*64 + qA*16 + hf*8 + q4*4;
                float4 w2 = *(const float4*)&wh2s[jb];
                float4 tp = *(const float4*)&e2ps[jb];
                float4 tn = *(const float4*)&e2ns[jb];
                float xs[4] = {w2.x, w2.y, w2.z, w2.w};
                float ps[4] = {tp.x, tp.y, tp.z, tp.w};
                float ns[4] = {tn.x, tn.y, tn.z, tn.w};
                float pe[4];
#pragma unroll
                for (int e = 0; e < 4; ++e) {
                    float tt = wh1r + xs[e];
                    bool pos = tt > 0.f;
                    pe[e] = (pos ? e1p : e1n) * (pos ? ps[e] : ns[e]);
                }
                unsigned bits = mask16 >> (hf*8 + q4*4);
#pragma unroll
                for (int p = 0; p < 2; ++p) {
                    unsigned w;
                    asm("v_cvt_pk_bf16_f32 %0, %1, %2" : "=v"(w) : "v"(pe[2*p]), "v"(pe[2*p+1]));
                    ob.w[q4*2 + p] = w & zlut[(bits >> (2*p)) & 3];
                }
            }
            *(bf16x8*)&At[abuf][rA*64 + (((qA*2 + hf) ^ rx)*8)] = ob.v;
        }
    };

#define MM(mi, ni, af, bf) acc[mi][ni] = __builtin_amdgcn_mfma_f32_16x16x32_bf16(af, bf, acc[mi][ni], 0, 0, 0)

    f32x4 acc[4][4];
#pragma unroll
    for (int x = 0; x < 4; ++x)
#pragma unroll
        for (int y = 0; y < 4; ++y) acc[x][y] = (f32x4)0.f;

    u64 mcur = pkbase[0];
    u64 mnext = pkbase[NN];
    __syncthreads();  // tables ready
    stageB(0, 0);
    stageB(1, 1);
    genA(0, 0, (unsigned)((mcur >> (qA*16)) & 0xffffu));
    asm volatile("s_waitcnt vmcnt(4) lgkmcnt(0)" ::: "memory");
    __builtin_amdgcn_s_barrier();

    int ibr = 0, ibs = 2;
#pragma unroll 1
    for (int kk = 0; kk < 32; ++kk) {
        int g = kk + 1;
        bool havef = (kk + 2 < 32);
        u64 mfut = 0;
        if (havef) mfut = pkbase[(size_t)(kk + 2)*NN];
        if (havef) stageB(kk + 2, ibs);
        if (g < 32) genA(g, g & 1, (unsigned)((mnext >> (qA*16)) & 0xffffu));
        int ra = kk & 1;
#pragma unroll
        for (int kc = 0; kc < 2; ++kc) {
            int jl = kc*4 + (lane >> 4);
            bf16x8 af[2], af2[2], bfr[4];
#pragma unroll
            for (int mi = 0; mi < 2; ++mi) {
                int rr2 = wm*64 + mi*16 + (lane & 15);
                af[mi] = *(const bf16x8*)&At[ra][rr2*64 + ((jl ^ (rr2 & 7))*8)];
            }
#pragma unroll
            for (int ni = 0; ni < 4; ++ni) {
                int rr2 = wn*64 + ni*16 + (lane & 15);
                bfr[ni] = *(const bf16x8*)&Bt[ibr][rr2*64 + ((jl ^ (rr2 & 7))*8)];
            }
            __builtin_amdgcn_s_setprio(1);
            MM(0,0,af[0],bfr[0]); MM(0,1,af[0],bfr[1]); MM(0,2,af[0],bfr[2]); MM(0,3,af[0],bfr[3]);
            MM(1,0,af[1],bfr[0]); MM(1,1,af[1],bfr[1]); MM(1,2,af[1],bfr[2]); MM(1,3,af[1],bfr[3]);
            __builtin_amdgcn_s_setprio(0);
#pragma unroll
            for (int mi = 2; mi < 4; ++mi) {
                int rr2 = wm*64 + mi*16 + (lane & 15);
                af2[mi-2] = *(const bf16x8*)&At[ra][rr2*64 + ((jl ^ (rr2 & 7))*8)];
            }
            __builtin_amdgcn_s_setprio(1);
            MM(2,0,af2[0],bfr[0]); MM(2,1,af2[0],bfr[1]); MM(2,2,af2[0],bfr[2]); MM(2,3,af2[0],bfr[3]);
            MM(3,0,af2[1],bfr[0]); MM(3,1,af2[1],bfr[1]); MM(3,2,af2[1],bfr[2]); MM(3,3,af2[1],bfr[3]);
            __builtin_amdgcn_s_setprio(0);
        }
        if (kk < 30) asm volatile("s_waitcnt vmcnt(4) lgkmcnt(0)" ::: "memory");
        else         asm volatile("s_waitcnt vmcnt(0) lgkmcnt(0)" ::: "memory");
        __builtin_amdgcn_s_barrier();
        if (havef) mnext = mfut;
        ibr = (ibr + 1 == 3) ? 0 : ibr + 1;
        ibs = (ibs + 1 == 3) ? 0 : ibs + 1;
    }
#undef MM

    float* ob2 = out + ((size_t)b*NN)*FF;
#pragma unroll
    for (int mi = 0; mi < 4; ++mi)
#pragma unroll
        for (int ni = 0; ni < 4; ++ni) {
            int o = wn*64 + ni*16 + (lane & 15);
#pragma unroll
            for (int rr = 0; rr < 4; ++rr) {
                int i = i0 + wm*64 + mi*16 + (lane >> 4)*4 + rr;
                float x = acc[mi][ni][rr];
                float y = (x > 0.f) ? x : (__builtin_amdgcn_exp2f(x*LOG2E) - 1.f);
                ob2[(size_t)i*FF + o] = y;
            }
        }
}

extern "C" void kernel_launch(void* const* d_in, const int* in_sizes, int n_in,
                              void* d_out, int out_size, void* d_ws, size_t ws_size,
                              hipStream_t stream) {
    const float* h   = (const float*)d_in[0];
    const int*   adj = (const int*)d_in[1];
    const float* W   = (const float*)d_in[2];
    const float* a   = (const float*)d_in[3];
    float* out = (float*)d_out;

    char* w = (char*)d_ws;
    const size_t MB = 1u << 20;
    u16* WT   = (u16*)(w + 0);            //  2 MB
    u16* WhT  = (u16*)(w + 2*MB);         // 16 MB  [16][256][2048] bf16
    u64* packed = (u64*)(w + 18*MB);      //  8 MB  [16][32 g][2048 i]
    float* pS  = (float*)(w + 26*MB);     //  8 MB  [16][64 chunk][2048 j]
    float* Wh1 = (float*)(w + 34*MB);                    // 128 KB (log2e-scaled)
    float* Wh2 = (float*)(w + 34*MB + 131072);           // 128 KB (log2e-scaled)
    float* u1  = (float*)(w + 34*MB + 2*131072);         //  16 KB
    float* u2  = (float*)(w + 34*MB + 2*131072 + 16384);

    k_prep_w<<<dim3(4, 16), 256, 0, stream>>>(W, a, WT, u1, u2);
    k_wh<<<dim3(512), 256, 0, stream>>>(h, WT, u1, u2, WhT, Wh1, Wh2);
    k_pack<<<dim3(64, 16), 256, 0, stream>>>(adj, Wh1, Wh2, pS, packed);
    k_gemm3<<<dim3(256), 512, 0, stream>>>(WhT, packed, Wh1, Wh2, pS, out);
}

// Round 17
// 158.413 us; speedup vs baseline: 1.0001x; 1.0001x over previous
//
#include <hip/hip_runtime.h>
#include <hip/hip_bf16.h>

typedef unsigned short u16;
typedef unsigned long long u64;
typedef __attribute__((ext_vector_type(8))) short bf16x8;
typedef __attribute__((ext_vector_type(4))) float f32x4;

#define NB 16
#define NN 2048
#define FF 256
#define LOG2E 1.4426950408889634f

__device__ __forceinline__ u16 f2bf(float x) {
    union { float f; unsigned u; } v; v.f = x;
    unsigned r = v.u + 0x7fffu + ((v.u >> 16) & 1u);
    return (u16)(r >> 16);
}

#define GLD_LDS(g, l) __builtin_amdgcn_global_load_lds((const __attribute__((address_space(1))) void*)(g), (__attribute__((address_space(3))) void*)(l), 16, 0, 0)

// ---------------- Kernel A: u1 = W@a1, u2 = W@a2 (fp32), WT = W^T in bf16 ----------------
__global__ __launch_bounds__(256) void k_prep_w(const float* __restrict__ W, const float* __restrict__ a,
                                                u16* __restrict__ WT, float* __restrict__ u1, float* __restrict__ u2) {
    int b = blockIdx.y, t = threadIdx.x;
    __shared__ float a1s[FF], a2s[FF];
    a1s[t] = a[b*2*FF + t];
    a2s[t] = a[b*2*FF + FF + t];
    __syncthreads();
    int f = blockIdx.x*64 + (t >> 2);
    int o0 = (t & 3) * 64;
    const float* wrow = W + (size_t)(b*FF + f)*FF + o0;
    u16* wtb = WT + (size_t)b*FF*FF;
    float s1 = 0.f, s2 = 0.f;
#pragma unroll
    for (int c = 0; c < 16; ++c) {
        float4 v = *(const float4*)(wrow + c*4);
        int o = o0 + c*4;
        s1 += v.x*a1s[o] + v.y*a1s[o+1] + v.z*a1s[o+2] + v.w*a1s[o+3];
        s2 += v.x*a2s[o] + v.y*a2s[o+1] + v.z*a2s[o+2] + v.w*a2s[o+3];
        wtb[(size_t)(o+0)*FF + f] = f2bf(v.x);
        wtb[(size_t)(o+1)*FF + f] = f2bf(v.y);
        wtb[(size_t)(o+2)*FF + f] = f2bf(v.z);
        wtb[(size_t)(o+3)*FF + f] = f2bf(v.w);
    }
    s1 += __shfl_xor(s1, 1); s1 += __shfl_xor(s1, 2);
    s2 += __shfl_xor(s2, 1); s2 += __shfl_xor(s2, 2);
    if ((t & 3) == 0) { u1[b*FF + f] = s1; u2[b*FF + f] = s2; }
}

// ---------------- Kernel B (fused): WhT = (h@W)^T bf16 (linear), Wh1/Wh2 fp32*log2e ----------------
__global__ __launch_bounds__(256) void k_wh(const float* __restrict__ h, const u16* __restrict__ WT,
                                            const float* __restrict__ u1, const float* __restrict__ u2,
                                            u16* __restrict__ WhT, float* __restrict__ Wh1, float* __restrict__ Wh2) {
    int bid = blockIdx.x;
    int nid = (bid & 7)*64 + (bid >> 3);
    int b  = nid >> 5;
    int i0 = (nid & 31) * 64;
    int t = threadIdx.x, lane = t & 63, wave = t >> 6;
    __shared__ alignas(16) u16 At[256*64];
    __shared__ alignas(16) u16 Bt[64*64];
    __shared__ float u1s[FF], u2s[FF];
    u1s[t] = u1[b*FF + t];
    u2s[t] = u2[b*FF + t];

    const u16*   WTb = WT + (size_t)b*FF*FF;
    const float* hb  = h + ((size_t)b*NN + i0)*FF;
    int r = t >> 2, q = t & 3, kq = q*16;

    f32x4 acc[4][4];
#pragma unroll
    for (int x = 0; x < 4; ++x)
#pragma unroll
        for (int y = 0; y < 4; ++y) acc[x][y] = (f32x4)0.f;
    float s1 = 0.f, s2 = 0.f;
    __syncthreads();

#pragma unroll 1
    for (int kk = 0; kk < 4; ++kk) {
        int k0 = kk*64;
#pragma unroll
        for (int is = 0; is < 8; ++is) {
            int s = is*256 + t;
            int row = s >> 3, jbp = s & 7;
            int jbl = jbp ^ (row & 7);
            GLD_LDS(WTb + (size_t)row*FF + k0 + jbl*8, &At[s*8]);
        }
        {
            const float* hp = hb + (size_t)r*FF + k0 + kq;
            float4 f0 = *(const float4*)(hp + 0);
            float4 f1 = *(const float4*)(hp + 4);
            float4 f2 = *(const float4*)(hp + 8);
            float4 f3 = *(const float4*)(hp + 12);
            float fv[16] = {f0.x,f0.y,f0.z,f0.w, f1.x,f1.y,f1.z,f1.w,
                            f2.x,f2.y,f2.z,f2.w, f3.x,f3.y,f3.z,f3.w};
            union { u16 u[16]; bf16x8 v[2]; } cv;
#pragma unroll
            for (int e = 0; e < 16; ++e) {
                int kidx = k0 + kq + e;
                s1 += fv[e]*u1s[kidx];
                s2 += fv[e]*u2s[kidx];
                cv.u[e] = f2bf(fv[e]);
            }
            int rx = r & 7;
            *(bf16x8*)&Bt[r*64 + ((q*2 + 0) ^ rx)*8] = cv.v[0];
            *(bf16x8*)&Bt[r*64 + ((q*2 + 1) ^ rx)*8] = cv.v[1];
        }
        __syncthreads();
#pragma unroll
        for (int kc = 0; kc < 2; ++kc) {
            int jl = kc*4 + (lane >> 4);
            bf16x8 af[4], bfr[4];
#pragma unroll
            for (int mi = 0; mi < 4; ++mi) {
                int rr2 = wave*64 + mi*16 + (lane & 15);
                af[mi] = *(const bf16x8*)&At[rr2*64 + ((jl ^ (rr2 & 7))*8)];
            }
#pragma unroll
            for (int ni = 0; ni < 4; ++ni) {
                int rr2 = ni*16 + (lane & 15);
                bfr[ni] = *(const bf16x8*)&Bt[rr2*64 + ((jl ^ (rr2 & 7))*8)];
            }
#pragma unroll
            for (int mi = 0; mi < 4; ++mi)
#pragma unroll
                for (int ni = 0; ni < 4; ++ni)
                    acc[mi][ni] = __builtin_amdgcn_mfma_f32_16x16x32_bf16(af[mi], bfr[ni], acc[mi][ni], 0, 0, 0);
        }
        __syncthreads();
    }
    s1 += __shfl_xor(s1, 1); s1 += __shfl_xor(s1, 2);
    s2 += __shfl_xor(s2, 1); s2 += __shfl_xor(s2, 2);
    if (q == 0) { Wh1[b*NN + i0 + r] = s1*LOG2E; Wh2[b*NN + i0 + r] = s2*LOG2E; }

    u16* Wo = WhT + (size_t)b*FF*NN;
#pragma unroll
    for (int mi = 0; mi < 4; ++mi)
#pragma unroll
        for (int ni = 0; ni < 4; ++ni) {
            int i = i0 + ni*16 + (lane & 15);
#pragma unroll
            for (int rr = 0; rr < 4; ++rr) {
                int o = wave*64 + mi*16 + (lane >> 4)*4 + rr;
                Wo[(size_t)o*NN + i] = f2bf(acc[mi][ni][rr]);
            }
        }
}

// ---------------- Kernel D: adj -> bitmask + separable exp-sums, 32-row chunks (4 blocks/CU) ----------------
__global__ __launch_bounds__(256) void k_pack(const int* __restrict__ adj, const float* __restrict__ Wh1,
                                              const float* __restrict__ Wh2, float* __restrict__ pS,
                                              u64* __restrict__ packed) {
    int b = blockIdx.y, ic = blockIdx.x;      // ic: 0..63, 32-row chunk
    int t = threadIdx.x;
    __shared__ float wh1s[32], e1ps[32], e1ns[32];
    __shared__ unsigned char mk[32][256];      // 8KB mask staging
    int ibase = ic*32;
    if (t < 32) {
        float w1 = Wh1[b*NN + ibase + t];
        wh1s[t] = w1;
        e1ps[t] = __builtin_amdgcn_exp2f(w1);
        e1ns[t] = __builtin_amdgcn_exp2f(0.2f*w1);
    }
    float w2[8];
    {
        float4 a0 = *(const float4*)(Wh2 + b*NN + t*8);
        float4 a1 = *(const float4*)(Wh2 + b*NN + t*8 + 4);
        w2[0]=a0.x; w2[1]=a0.y; w2[2]=a0.z; w2[3]=a0.w;
        w2[4]=a1.x; w2[5]=a1.y; w2[6]=a1.z; w2[7]=a1.w;
    }
    __syncthreads();
    const int* abase = adj + ((size_t)(b*NN + ibase))*NN + t*8;
    float sp[8] = {0.f,0.f,0.f,0.f,0.f,0.f,0.f,0.f};
    float sn[8] = {0.f,0.f,0.f,0.f,0.f,0.f,0.f,0.f};
#pragma unroll 1
    for (int r4 = 0; r4 < 8; ++r4) {
        int4 v[4][2];
#pragma unroll
        for (int k = 0; k < 4; ++k) {
            v[k][0] = *(const int4*)(abase + (size_t)(r4*4 + k)*NN);
            v[k][1] = *(const int4*)(abase + (size_t)(r4*4 + k)*NN + 4);
        }
#pragma unroll
        for (int k = 0; k < 4; ++k) {
            int row = r4*4 + k;
            float w1 = wh1s[row], ep = e1ps[row], en = e1ns[row];
            int a[8] = {v[k][0].x, v[k][0].y, v[k][0].z, v[k][0].w,
                        v[k][1].x, v[k][1].y, v[k][1].z, v[k][1].w};
            unsigned bits = 0;
#pragma unroll
            for (int e = 0; e < 8; ++e) {
                bool bit = a[e] > 0;
                bool pos = (w1 + w2[e]) > 0.f;
                bits |= bit ? (1u << e) : 0u;
                sp[e] += (bit && pos)  ? ep : 0.f;
                sn[e] += (bit && !pos) ? en : 0.f;
            }
            mk[row][t] = (unsigned char)bits;
        }
    }
    __syncthreads();
    // flush masks: g = t>>3 (0..31), rows (t&7)*4 .. +3 (32B contiguous per thread)
    {
        int g = t >> 3, r0 = (t & 7)*4;
        u64* dst = packed + ((size_t)(b*32 + g))*NN + ibase + r0;
#pragma unroll
        for (int k = 0; k < 4; ++k)
            dst[k] = *(const u64*)&mk[r0 + k][g*8];
    }
    // partial sums for this 32-row chunk
    {
        float o8[8];
#pragma unroll
        for (int e = 0; e < 8; ++e) {
            float E2p = __builtin_amdgcn_exp2f(w2[e]);
            float E2n = __builtin_amdgcn_exp2f(0.2f*w2[e]);
            o8[e] = E2p*sp[e] + E2n*sn[e];
        }
        float4* po = (float4*)(pS + ((size_t)(b*64 + ic))*NN + t*8);
        po[0] = make_float4(o8[0],o8[1],o8[2],o8[3]);
        po[1] = make_float4(o8[4],o8[5],o8[6],o8[7]);
    }
}

// ---------------- Kernel F: out = elu( att @ Wh ), R13 config, separable-exp genA ----------------
__global__ __launch_bounds__(512, 1) void k_gemm3(const u16* __restrict__ WhT, const u64* __restrict__ packed,
                                                  const float* __restrict__ Wh1, const float* __restrict__ Wh2,
                                                  const float* __restrict__ pS, float* __restrict__ out) {
    int bid = blockIdx.x;
    int nid = (bid & 7)*32 + (bid >> 3);
    int b  = nid >> 4;
    int i0 = (nid & 15) * 128;
    int t = threadIdx.x, lane = t & 63, wave = t >> 6;
    int wm = wave >> 2, wn = wave & 3;
    __shared__ alignas(16) u16 At[2][128*64];
    __shared__ alignas(16) u16 Bt[3][256*64];
    __shared__ float wh2s[NN];
    __shared__ float e2ps[NN];
    __shared__ float e2ns[NN];
    __shared__ unsigned zlut[4];

    const u16* Wo = WhT + (size_t)b*FF*NN;
    int rA = t >> 2, qA = t & 3;
    const u64* pkbase = packed + (size_t)b*32*NN + i0 + rA;   // tile g mask at pkbase[g*NN]

    float wh1r = Wh1[b*NN + i0 + rA];
    float e1p = __builtin_amdgcn_exp2f(wh1r);
    float e1n = __builtin_amdgcn_exp2f(0.2f*wh1r);

    // tables: vectorized sum over 64 partial chunks (L2-hot), then exp2 once per j
    {
        int idx = t*4;
        float4 s4 = make_float4(0.f, 0.f, 0.f, 0.f);
        const float* pb = pS + (size_t)b*64*NN + idx;
#pragma unroll 1
        for (int cc = 0; cc < 64; ++cc) {
            float4 v = *(const float4*)(pb + (size_t)cc*NN);
            s4.x += v.x; s4.y += v.y; s4.z += v.z; s4.w += v.w;
        }
        float4 w2v = *(const float4*)(Wh2 + b*NN + idx);
        float sv[4] = {s4.x, s4.y, s4.z, s4.w};
        float wv[4] = {w2v.x, w2v.y, w2v.z, w2v.w};
#pragma unroll
        for (int e = 0; e < 4; ++e) {
            float inv = (sv[e] > 0.f) ? 1.0f/sv[e] : 0.0f;
            wh2s[idx + e] = wv[e];
            e2ps[idx + e] = __builtin_amdgcn_exp2f(wv[e]) * inv;
            e2ns[idx + e] = __builtin_amdgcn_exp2f(0.2f*wv[e]) * inv;
        }
    }
    if (t < 4) zlut[t] = ((t & 1) ? 0xFFFFu : 0u) | ((t & 2) ? 0xFFFF0000u : 0u);

    auto stageB = [&](int kk, int bbuf) {
        int k0 = kk*64;
#pragma unroll
        for (int is = 0; is < 4; ++is) {
            int s = is*512 + t;
            int row = s >> 3, jbp = s & 7;
            int jbl = jbp ^ (row & 7);
            GLD_LDS(Wo + (size_t)row*NN + k0 + jbl*8, &Bt[bbuf][s*8]);
        }
    };
    auto genA = [&](int g, int abuf, unsigned mask16) {
        int rx = rA & 7;
#pragma unroll
        for (int hf = 0; hf < 2; ++hf) {
            union { unsigned w[4]; bf16x8 v; } ob;
#pragma unroll
            for (int q4 = 0; q4 < 2; ++q4) {
                int jb = g*64 + qA*16 + hf*8 + q4*4;
                float4 w2 = *(const float4*)&wh2s[jb];
                float4 tp = *(const float4*)&e2ps[jb];
                float4 tn = *(const float4*)&e2ns[jb];
                float xs[4] = {w2.x, w2.y, w2.z, w2.w};
                float ps[4] = {tp.x, tp.y, tp.z, tp.w};
                float ns[4] = {tn.x, tn.y, tn.z, tn.w};
                float pe[4];
#pragma unroll
                for (int e = 0; e < 4; ++e) {
                    float tt = wh1r + xs[e];
                    bool pos = tt > 0.f;
                    pe[e] = (pos ? e1p : e1n) * (pos ? ps[e] : ns[e]);
                }
                unsigned bits = mask16 >> (hf*8 + q4*4);
#pragma unroll
                for (int p = 0; p < 2; ++p) {
                    unsigned w;
                    asm("v_cvt_pk_bf16_f32 %0, %1, %2" : "=v"(w) : "v"(pe[2*p]), "v"(pe[2*p+1]));
                    ob.w[q4*2 + p] = w & zlut[(bits >> (2*p)) & 3];
                }
            }
            *(bf16x8*)&At[abuf][rA*64 + (((qA*2 + hf) ^ rx)*8)] = ob.v;
        }
    };

#define MM(mi, ni, af, bf) acc[mi][ni] = __builtin_amdgcn_mfma_f32_16x16x32_bf16(af, bf, acc[mi][ni], 0, 0, 0)

    f32x4 acc[4][4];
#pragma unroll
    for (int x = 0; x < 4; ++x)
#pragma unroll
        for (int y = 0; y < 4; ++y) acc[x][y] = (f32x4)0.f;

    u64 mcur = pkbase[0];
    u64 mnext = pkbase[NN];
    __syncthreads();  // tables ready
    stageB(0, 0);
    stageB(1, 1);
    genA(0, 0, (unsigned)((mcur >> (qA*16)) & 0xffffu));
    asm volatile("s_waitcnt vmcnt(4) lgkmcnt(0)" ::: "memory");
    __builtin_amdgcn_s_barrier();

    int ibr = 0, ibs = 2;
#pragma unroll 1
    for (int kk = 0; kk < 32; ++kk) {
        int g = kk + 1;
        bool havef = (kk + 2 < 32);
        u64 mfut = 0;
        if (havef) mfut = pkbase[(size_t)(kk + 2)*NN];
        if (havef) stageB(kk + 2, ibs);
        if (g < 32) genA(g, g & 1, (unsigned)((mnext >> (qA*16)) & 0xffffu));
        int ra = kk & 1;
#pragma unroll
        for (int kc = 0; kc < 2; ++kc) {
            int jl = kc*4 + (lane >> 4);
            bf16x8 af[2], af2[2], bfr[4];
#pragma unroll
            for (int mi = 0; mi < 2; ++mi) {
                int rr2 = wm*64 + mi*16 + (lane & 15);
                af[mi] = *(const bf16x8*)&At[ra][rr2*64 + ((jl ^ (rr2 & 7))*8)];
            }
#pragma unroll
            for (int ni = 0; ni < 4; ++ni) {
                int rr2 = wn*64 + ni*16 + (lane & 15);
                bfr[ni] = *(const bf16x8*)&Bt[ibr][rr2*64 + ((jl ^ (rr2 & 7))*8)];
            }
            __builtin_amdgcn_s_setprio(1);
            MM(0,0,af[0],bfr[0]); MM(0,1,af[0],bfr[1]); MM(0,2,af[0],bfr[2]); MM(0,3,af[0],bfr[3]);
            MM(1,0,af[1],bfr[0]); MM(1,1,af[1],bfr[1]); MM(1,2,af[1],bfr[2]); MM(1,3,af[1],bfr[3]);
            __builtin_amdgcn_s_setprio(0);
#pragma unroll
            for (int mi = 2; mi < 4; ++mi) {
                int rr2 = wm*64 + mi*16 + (lane & 15);
                af2[mi-2] = *(const bf16x8*)&At[ra][rr2*64 + ((jl ^ (rr2 & 7))*8)];
            }
            __builtin_amdgcn_s_setprio(1);
            MM(2,0,af2[0],bfr[0]); MM(2,1,af2[0],bfr[1]); MM(2,2,af2[0],bfr[2]); MM(2,3,af2[0],bfr[3]);
            MM(3,0,af2[1],bfr[0]); MM(3,1,af2[1],bfr[1]); MM(3,2,af2[1],bfr[2]); MM(3,3,af2[1],bfr[3]);
            __builtin_amdgcn_s_setprio(0);
        }
        if (kk < 30) asm volatile("s_waitcnt vmcnt(4) lgkmcnt(0)" ::: "memory");
        else         asm volatile("s_waitcnt vmcnt(0) lgkmcnt(0)" ::: "memory");
        __builtin_amdgcn_s_barrier();
        if (havef) mnext = mfut;
        ibr = (ibr + 1 == 3) ? 0 : ibr + 1;
        ibs = (ibs + 1 == 3) ? 0 : ibs + 1;
    }
#undef MM

    float* ob2 = out + ((size_t)b*NN)*FF;
#pragma unroll
    for (int mi = 0; mi < 4; ++mi)
#pragma unroll
        for (int ni = 0; ni < 4; ++ni) {
            int o = wn*64 + ni*16 + (lane & 15);
#pragma unroll
            for (int rr = 0; rr < 4; ++rr) {
                int i = i0 + wm*64 + mi*16 + (lane >> 4)*4 + rr;
                float x = acc[mi][ni][rr];
                float y = (x > 0.f) ? x : (__builtin_amdgcn_exp2f(x*LOG2E) - 1.f);
                ob2[(size_t)i*FF + o] = y;
            }
        }
}

extern "C" void kernel_launch(void* const* d_in, const int* in_sizes, int n_in,
                              void* d_out, int out_size, void* d_ws, size_t ws_size,
                              hipStream_t stream) {
    const float* h   = (const float*)d_in[0];
    const int*   adj = (const int*)d_in[1];
    const float* W   = (const float*)d_in[2];
    const float* a   = (const float*)d_in[3];
    float* out = (float*)d_out;

    char* w = (char*)d_ws;
    const size_t MB = 1u << 20;
    u16* WT   = (u16*)(w + 0);            //  2 MB
    u16* WhT  = (u16*)(w + 2*MB);         // 16 MB  [16][256][2048] bf16
    u64* packed = (u64*)(w + 18*MB);      //  8 MB  [16][32 g][2048 i]
    float* pS  = (float*)(w + 26*MB);     //  8 MB  [16][64 chunk][2048 j]
    float* Wh1 = (float*)(w + 34*MB);                    // 128 KB (log2e-scaled)
    float* Wh2 = (float*)(w + 34*MB + 131072);           // 128 KB (log2e-scaled)
    float* u1  = (float*)(w + 34*MB + 2*131072);         //  16 KB
    float* u2  = (float*)(w + 34*MB + 2*131072 + 16384);

    k_prep_w<<<dim3(4, 16), 256, 0, stream>>>(W, a, WT, u1, u2);
    k_wh<<<dim3(512), 256, 0, stream>>>(h, WT, u1, u2, WhT, Wh1, Wh2);
    k_pack<<<dim3(64, 16), 256, 0, stream>>>(adj, Wh1, Wh2, pS, packed);
    k_gemm3<<<dim3(256), 512, 0, stream>>>(WhT, packed, Wh1, Wh2, pS, out);
}

// Round 18
// 149.063 us; speedup vs baseline: 1.0628x; 1.0627x over previous
//
#include <hip/hip_runtime.h>
#include <hip/hip_bf16.h>

typedef unsigned short u16;
typedef unsigned long long u64;
typedef __attribute__((ext_vector_type(8))) short bf16x8;
typedef __attribute__((ext_vector_type(4))) float f32x4;

#define NB 16
#define NN 2048
#define FF 256
#define LOG2E 1.4426950408889634f

__device__ __forceinline__ u16 f2bf(float x) {
    union { float f; unsigned u; } v; v.f = x;
    unsigned r = v.u + 0x7fffu + ((v.u >> 16) & 1u);
    return (u16)(r >> 16);
}

#define GLD_LDS(g, l) __builtin_amdgcn_global_load_lds((const __attribute__((address_space(1))) void*)(g), (__attribute__((address_space(3))) void*)(l), 16, 0, 0)

// ---------------- Kernel A: u1 = W@a1, u2 = W@a2 (fp32), WT = W^T in bf16 ----------------
__global__ __launch_bounds__(256) void k_prep_w(const float* __restrict__ W, const float* __restrict__ a,
                                                u16* __restrict__ WT, float* __restrict__ u1, float* __restrict__ u2) {
    int b = blockIdx.y, t = threadIdx.x;
    __shared__ float a1s[FF], a2s[FF];
    a1s[t] = a[b*2*FF + t];
    a2s[t] = a[b*2*FF + FF + t];
    __syncthreads();
    int f = blockIdx.x*64 + (t >> 2);
    int o0 = (t & 3) * 64;
    const float* wrow = W + (size_t)(b*FF + f)*FF + o0;
    u16* wtb = WT + (size_t)b*FF*FF;
    float s1 = 0.f, s2 = 0.f;
#pragma unroll
    for (int c = 0; c < 16; ++c) {
        float4 v = *(const float4*)(wrow + c*4);
        int o = o0 + c*4;
        s1 += v.x*a1s[o] + v.y*a1s[o+1] + v.z*a1s[o+2] + v.w*a1s[o+3];
        s2 += v.x*a2s[o] + v.y*a2s[o+1] + v.z*a2s[o+2] + v.w*a2s[o+3];
        wtb[(size_t)(o+0)*FF + f] = f2bf(v.x);
        wtb[(size_t)(o+1)*FF + f] = f2bf(v.y);
        wtb[(size_t)(o+2)*FF + f] = f2bf(v.z);
        wtb[(size_t)(o+3)*FF + f] = f2bf(v.w);
    }
    s1 += __shfl_xor(s1, 1); s1 += __shfl_xor(s1, 2);
    s2 += __shfl_xor(s2, 1); s2 += __shfl_xor(s2, 2);
    if ((t & 3) == 0) { u1[b*FF + f] = s1; u2[b*FF + f] = s2; }
}

// ---------------- Kernel B (fused): WhT = (h@W)^T bf16 (linear), Wh1/Wh2 fp32*log2e ----------------
__global__ __launch_bounds__(256) void k_wh(const float* __restrict__ h, const u16* __restrict__ WT,
                                            const float* __restrict__ u1, const float* __restrict__ u2,
                                            u16* __restrict__ WhT, float* __restrict__ Wh1, float* __restrict__ Wh2) {
    int bid = blockIdx.x;
    int nid = (bid & 7)*64 + (bid >> 3);
    int b  = nid >> 5;
    int i0 = (nid & 31) * 64;
    int t = threadIdx.x, lane = t & 63, wave = t >> 6;
    __shared__ alignas(16) u16 At[256*64];
    __shared__ alignas(16) u16 Bt[64*64];
    __shared__ float u1s[FF], u2s[FF];
    u1s[t] = u1[b*FF + t];
    u2s[t] = u2[b*FF + t];

    const u16*   WTb = WT + (size_t)b*FF*FF;
    const float* hb  = h + ((size_t)b*NN + i0)*FF;
    int r = t >> 2, q = t & 3, kq = q*16;

    f32x4 acc[4][4];
#pragma unroll
    for (int x = 0; x < 4; ++x)
#pragma unroll
        for (int y = 0; y < 4; ++y) acc[x][y] = (f32x4)0.f;
    float s1 = 0.f, s2 = 0.f;
    __syncthreads();

#pragma unroll 1
    for (int kk = 0; kk < 4; ++kk) {
        int k0 = kk*64;
#pragma unroll
        for (int is = 0; is < 8; ++is) {
            int s = is*256 + t;
            int row = s >> 3, jbp = s & 7;
            int jbl = jbp ^ (row & 7);
            GLD_LDS(WTb + (size_t)row*FF + k0 + jbl*8, &At[s*8]);
        }
        {
            const float* hp = hb + (size_t)r*FF + k0 + kq;
            float4 f0 = *(const float4*)(hp + 0);
            float4 f1 = *(const float4*)(hp + 4);
            float4 f2 = *(const float4*)(hp + 8);
            float4 f3 = *(const float4*)(hp + 12);
            float fv[16] = {f0.x,f0.y,f0.z,f0.w, f1.x,f1.y,f1.z,f1.w,
                            f2.x,f2.y,f2.z,f2.w, f3.x,f3.y,f3.z,f3.w};
            union { u16 u[16]; bf16x8 v[2]; } cv;
#pragma unroll
            for (int e = 0; e < 16; ++e) {
                int kidx = k0 + kq + e;
                s1 += fv[e]*u1s[kidx];
                s2 += fv[e]*u2s[kidx];
                cv.u[e] = f2bf(fv[e]);
            }
            int rx = r & 7;
            *(bf16x8*)&Bt[r*64 + ((q*2 + 0) ^ rx)*8] = cv.v[0];
            *(bf16x8*)&Bt[r*64 + ((q*2 + 1) ^ rx)*8] = cv.v[1];
        }
        __syncthreads();
#pragma unroll
        for (int kc = 0; kc < 2; ++kc) {
            int jl = kc*4 + (lane >> 4);
            bf16x8 af[4], bfr[4];
#pragma unroll
            for (int mi = 0; mi < 4; ++mi) {
                int rr2 = wave*64 + mi*16 + (lane & 15);
                af[mi] = *(const bf16x8*)&At[rr2*64 + ((jl ^ (rr2 & 7))*8)];
            }
#pragma unroll
            for (int ni = 0; ni < 4; ++ni) {
                int rr2 = ni*16 + (lane & 15);
                bfr[ni] = *(const bf16x8*)&Bt[rr2*64 + ((jl ^ (rr2 & 7))*8)];
            }
#pragma unroll
            for (int mi = 0; mi < 4; ++mi)
#pragma unroll
                for (int ni = 0; ni < 4; ++ni)
                    acc[mi][ni] = __builtin_amdgcn_mfma_f32_16x16x32_bf16(af[mi], bfr[ni], acc[mi][ni], 0, 0, 0);
        }
        __syncthreads();
    }
    s1 += __shfl_xor(s1, 1); s1 += __shfl_xor(s1, 2);
    s2 += __shfl_xor(s2, 1); s2 += __shfl_xor(s2, 2);
    if (q == 0) { Wh1[b*NN + i0 + r] = s1*LOG2E; Wh2[b*NN + i0 + r] = s2*LOG2E; }

    u16* Wo = WhT + (size_t)b*FF*NN;
#pragma unroll
    for (int mi = 0; mi < 4; ++mi)
#pragma unroll
        for (int ni = 0; ni < 4; ++ni) {
            int i = i0 + ni*16 + (lane & 15);
#pragma unroll
            for (int rr = 0; rr < 4; ++rr) {
                int o = wave*64 + mi*16 + (lane >> 4)*4 + rr;
                Wo[(size_t)o*NN + i] = f2bf(acc[mi][ni][rr]);
            }
        }
}

// ---------------- Kernel D: adj -> bitmask + separable exp-sums (R13 k_pack, 64-row chunks) ----------------
__global__ __launch_bounds__(256) void k_pack(const int* __restrict__ adj, const float* __restrict__ Wh1,
                                              const float* __restrict__ Wh2, float* __restrict__ pS,
                                              u64* __restrict__ packed) {
    int b = blockIdx.y, ic = blockIdx.x;      // ic: 0..31, 64-row chunk
    int t = threadIdx.x;
    __shared__ float wh1s[64], e1ps[64], e1ns[64];
    __shared__ unsigned char mk[64][264];      // +8B/row pad: flush read was 8-way bank conflict
    int ibase = ic*64;
    if (t < 64) {
        float w1 = Wh1[b*NN + ibase + t];
        wh1s[t] = w1;
        e1ps[t] = __builtin_amdgcn_exp2f(w1);
        e1ns[t] = __builtin_amdgcn_exp2f(0.2f*w1);
    }
    float w2[8];
    {
        float4 a0 = *(const float4*)(Wh2 + b*NN + t*8);
        float4 a1 = *(const float4*)(Wh2 + b*NN + t*8 + 4);
        w2[0]=a0.x; w2[1]=a0.y; w2[2]=a0.z; w2[3]=a0.w;
        w2[4]=a1.x; w2[5]=a1.y; w2[6]=a1.z; w2[7]=a1.w;
    }
    __syncthreads();
    const int* abase = adj + ((size_t)(b*NN + ibase))*NN + t*8;
    float sp[8] = {0.f,0.f,0.f,0.f,0.f,0.f,0.f,0.f};
    float sn[8] = {0.f,0.f,0.f,0.f,0.f,0.f,0.f,0.f};
#pragma unroll 1
    for (int r4 = 0; r4 < 16; ++r4) {
        int4 v[4][2];
#pragma unroll
        for (int k = 0; k < 4; ++k) {
            v[k][0] = *(const int4*)(abase + (size_t)(r4*4 + k)*NN);
            v[k][1] = *(const int4*)(abase + (size_t)(r4*4 + k)*NN + 4);
        }
#pragma unroll
        for (int k = 0; k < 4; ++k) {
            int row = r4*4 + k;
            float w1 = wh1s[row], ep = e1ps[row], en = e1ns[row];
            int a[8] = {v[k][0].x, v[k][0].y, v[k][0].z, v[k][0].w,
                        v[k][1].x, v[k][1].y, v[k][1].z, v[k][1].w};
            unsigned bits = 0;
#pragma unroll
            for (int e = 0; e < 8; ++e) {
                bool bit = a[e] > 0;
                bool pos = (w1 + w2[e]) > 0.f;
                bits |= bit ? (1u << e) : 0u;
                sp[e] += (bit && pos)  ? ep : 0.f;
                sn[e] += (bit && !pos) ? en : 0.f;
            }
            mk[row][t] = (unsigned char)bits;
        }
    }
    __syncthreads();
    {
        int g = t >> 3, r0 = (t & 7)*8;
        u64* dst = packed + ((size_t)(b*32 + g))*NN + ibase + r0;
#pragma unroll
        for (int k = 0; k < 8; ++k)
            dst[k] = *(const u64*)&mk[r0 + k][g*8];
    }
    {
        float o8[8];
#pragma unroll
        for (int e = 0; e < 8; ++e) {
            float E2p = __builtin_amdgcn_exp2f(w2[e]);
            float E2n = __builtin_amdgcn_exp2f(0.2f*w2[e]);
            o8[e] = E2p*sp[e] + E2n*sn[e];
        }
        float4* po = (float4*)(pS + ((size_t)(b*32 + ic))*NN + t*8);
        po[0] = make_float4(o8[0],o8[1],o8[2],o8[3]);
        po[1] = make_float4(o8[4],o8[5],o8[6],o8[7]);
    }
}

// ---------------- Kernel F: out = elu( att @ Wh ), R13 config, separable-exp genA ----------------
__global__ __launch_bounds__(512, 1) void k_gemm3(const u16* __restrict__ WhT, const u64* __restrict__ packed,
                                                  const float* __restrict__ Wh1, const float* __restrict__ Wh2,
                                                  const float* __restrict__ pS, float* __restrict__ out) {
    int bid = blockIdx.x;
    int nid = (bid & 7)*32 + (bid >> 3);
    int b  = nid >> 4;
    int i0 = (nid & 15) * 128;
    int t = threadIdx.x, lane = t & 63, wave = t >> 6;
    int wm = wave >> 2, wn = wave & 3;
    __shared__ alignas(16) u16 At[2][128*64];
    __shared__ alignas(16) u16 Bt[3][256*64];
    __shared__ float wh2s[NN];
    __shared__ float e2ps[NN];
    __shared__ float e2ns[NN];
    __shared__ unsigned zlut[4];

    const u16* Wo = WhT + (size_t)b*FF*NN;
    int rA = t >> 2, qA = t & 3;
    const u64* pkbase = packed + (size_t)b*32*NN + i0 + rA;   // tile g mask at pkbase[g*NN]

    float wh1r = Wh1[b*NN + i0 + rA];
    float e1p = __builtin_amdgcn_exp2f(wh1r);
    float e1n = __builtin_amdgcn_exp2f(0.2f*wh1r);

#pragma unroll
    for (int c = 0; c < 4; ++c) {
        int idx = c*512 + t;
        float w2 = Wh2[b*NN + idx];
        float s = 0.f;
#pragma unroll
        for (int cc = 0; cc < 32; ++cc) s += pS[((size_t)(b*32 + cc))*NN + idx];
        float inv = (s > 0.f) ? 1.0f/s : 0.0f;
        wh2s[idx] = w2;
        e2ps[idx] = __builtin_amdgcn_exp2f(w2) * inv;
        e2ns[idx] = __builtin_amdgcn_exp2f(0.2f*w2) * inv;
    }
    if (t < 4) zlut[t] = ((t & 1) ? 0xFFFFu : 0u) | ((t & 2) ? 0xFFFF0000u : 0u);

    auto stageB = [&](int kk, int bbuf) {
        int k0 = kk*64;
#pragma unroll
        for (int is = 0; is < 4; ++is) {
            int s = is*512 + t;
            int row = s >> 3, jbp = s & 7;
            int jbl = jbp ^ (row & 7);
            GLD_LDS(Wo + (size_t)row*NN + k0 + jbl*8, &Bt[bbuf][s*8]);
        }
    };
    auto genA = [&](int g, int abuf, unsigned mask16) {
        int rx = rA & 7;
#pragma unroll
        for (int hf = 0; hf < 2; ++hf) {
            union { unsigned w[4]; bf16x8 v; } ob;
#pragma unroll
            for (int q4 = 0; q4 < 2; ++q4) {
                int jb = g*64 + qA*16 + hf*8 + q4*4;
                float4 w2 = *(const float4*)&wh2s[jb];
                float4 tp = *(const float4*)&e2ps[jb];
                float4 tn = *(const float4*)&e2ns[jb];
                float xs[4] = {w2.x, w2.y, w2.z, w2.w};
                float ps[4] = {tp.x, tp.y, tp.z, tp.w};
                float ns[4] = {tn.x, tn.y, tn.z, tn.w};
                float pe[4];
#pragma unroll
                for (int e = 0; e < 4; ++e) {
                    float tt = wh1r + xs[e];
                    bool pos = tt > 0.f;
                    pe[e] = (pos ? e1p : e1n) * (pos ? ps[e] : ns[e]);
                }
                unsigned bits = mask16 >> (hf*8 + q4*4);
#pragma unroll
                for (int p = 0; p < 2; ++p) {
                    unsigned w;
                    asm("v_cvt_pk_bf16_f32 %0, %1, %2" : "=v"(w) : "v"(pe[2*p]), "v"(pe[2*p+1]));
                    ob.w[q4*2 + p] = w & zlut[(bits >> (2*p)) & 3];
                }
            }
            *(bf16x8*)&At[abuf][rA*64 + (((qA*2 + hf) ^ rx)*8)] = ob.v;
        }
    };

#define MM(mi, ni, af, bf) acc[mi][ni] = __builtin_amdgcn_mfma_f32_16x16x32_bf16(af, bf, acc[mi][ni], 0, 0, 0)

    f32x4 acc[4][4];
#pragma unroll
    for (int x = 0; x < 4; ++x)
#pragma unroll
        for (int y = 0; y < 4; ++y) acc[x][y] = (f32x4)0.f;

    u64 mcur = pkbase[0];
    u64 mnext = pkbase[NN];
    __syncthreads();  // tables ready
    stageB(0, 0);
    stageB(1, 1);
    genA(0, 0, (unsigned)((mcur >> (qA*16)) & 0xffffu));
    asm volatile("s_waitcnt vmcnt(4) lgkmcnt(0)" ::: "memory");
    __builtin_amdgcn_s_barrier();

    int ibr = 0, ibs = 2;
#pragma unroll 1
    for (int kk = 0; kk < 32; ++kk) {
        int g = kk + 1;
        bool havef = (kk + 2 < 32);
        u64 mfut = 0;
        if (havef) mfut = pkbase[(size_t)(kk + 2)*NN];
        if (havef) stageB(kk + 2, ibs);
        if (g < 32) genA(g, g & 1, (unsigned)((mnext >> (qA*16)) & 0xffffu));
        int ra = kk & 1;
#pragma unroll
        for (int kc = 0; kc < 2; ++kc) {
            int jl = kc*4 + (lane >> 4);
            bf16x8 af[2], af2[2], bfr[4];
#pragma unroll
            for (int mi = 0; mi < 2; ++mi) {
                int rr2 = wm*64 + mi*16 + (lane & 15);
                af[mi] = *(const bf16x8*)&At[ra][rr2*64 + ((jl ^ (rr2 & 7))*8)];
            }
#pragma unroll
            for (int ni = 0; ni < 4; ++ni) {
                int rr2 = wn*64 + ni*16 + (lane & 15);
                bfr[ni] = *(const bf16x8*)&Bt[ibr][rr2*64 + ((jl ^ (rr2 & 7))*8)];
            }
            __builtin_amdgcn_s_setprio(1);
            MM(0,0,af[0],bfr[0]); MM(0,1,af[0],bfr[1]); MM(0,2,af[0],bfr[2]); MM(0,3,af[0],bfr[3]);
            MM(1,0,af[1],bfr[0]); MM(1,1,af[1],bfr[1]); MM(1,2,af[1],bfr[2]); MM(1,3,af[1],bfr[3]);
            __builtin_amdgcn_s_setprio(0);
#pragma unroll
            for (int mi = 2; mi < 4; ++mi) {
                int rr2 = wm*64 + mi*16 + (lane & 15);
                af2[mi-2] = *(const bf16x8*)&At[ra][rr2*64 + ((jl ^ (rr2 & 7))*8)];
            }
            __builtin_amdgcn_s_setprio(1);
            MM(2,0,af2[0],bfr[0]); MM(2,1,af2[0],bfr[1]); MM(2,2,af2[0],bfr[2]); MM(2,3,af2[0],bfr[3]);
            MM(3,0,af2[1],bfr[0]); MM(3,1,af2[1],bfr[1]); MM(3,2,af2[1],bfr[2]); MM(3,3,af2[1],bfr[3]);
            __builtin_amdgcn_s_setprio(0);
        }
        if (kk < 30) asm volatile("s_waitcnt vmcnt(4) lgkmcnt(0)" ::: "memory");
        else         asm volatile("s_waitcnt vmcnt(0) lgkmcnt(0)" ::: "memory");
        __builtin_amdgcn_s_barrier();
        if (havef) mnext = mfut;
        ibr = (ibr + 1 == 3) ? 0 : ibr + 1;
        ibs = (ibs + 1 == 3) ? 0 : ibs + 1;
    }
#undef MM

    float* ob2 = out + ((size_t)b*NN)*FF;
#pragma unroll
    for (int mi = 0; mi < 4; ++mi)
#pragma unroll
        for (int ni = 0; ni < 4; ++ni) {
            int o = wn*64 + ni*16 + (lane & 15);
#pragma unroll
            for (int rr = 0; rr < 4; ++rr) {
                int i = i0 + wm*64 + mi*16 + (lane >> 4)*4 + rr;
                float x = acc[mi][ni][rr];
                float y = (x > 0.f) ? x : (__builtin_amdgcn_exp2f(x*LOG2E) - 1.f);
                ob2[(size_t)i*FF + o] = y;
            }
        }
}

extern "C" void kernel_launch(void* const* d_in, const int* in_sizes, int n_in,
                              void* d_out, int out_size, void* d_ws, size_t ws_size,
                              hipStream_t stream) {
    const float* h   = (const float*)d_in[0];
    const int*   adj = (const int*)d_in[1];
    const float* W   = (const float*)d_in[2];
    const float* a   = (const float*)d_in[3];
    float* out = (float*)d_out;

    char* w = (char*)d_ws;
    const size_t MB = 1u << 20;
    u16* WT   = (u16*)(w + 0);            //  2 MB
    u16* WhT  = (u16*)(w + 2*MB);         // 16 MB  [16][256][2048] bf16
    u64* packed = (u64*)(w + 18*MB);      //  8 MB  [16][32 g][2048 i]
    float* pS  = (float*)(w + 26*MB);     //  4 MB  [16][32 chunk][2048 j]
    float* Wh1 = (float*)(w + 34*MB);                    // 128 KB (log2e-scaled)
    float* Wh2 = (float*)(w + 34*MB + 131072);           // 128 KB (log2e-scaled)
    float* u1  = (float*)(w + 34*MB + 2*131072);         //  16 KB
    float* u2  = (float*)(w + 34*MB + 2*131072 + 16384);

    k_prep_w<<<dim3(4, 16), 256, 0, stream>>>(W, a, WT, u1, u2);
    k_wh<<<dim3(512), 256, 0, stream>>>(h, WT, u1, u2, WhT, Wh1, Wh2);
    k_pack<<<dim3(32, 16), 256, 0, stream>>>(adj, Wh1, Wh2, pS, packed);
    k_gemm3<<<dim3(256), 512, 0, stream>>>(WhT, packed, Wh1, Wh2, pS, out);
}